// Round 1
// baseline (911.533 us; speedup 1.0000x reference)
//
#include <hip/hip_runtime.h>
#include <math.h>

#define Bsz 32
#define Hd  1024
#define Sd  512
#define Vd  32000

typedef __attribute__((ext_vector_type(8))) short v8s;
typedef __attribute__((ext_vector_type(4))) float v4f;

__device__ __forceinline__ float sigf(float x){ return 1.0f/(1.0f+__expf(-x)); }
__device__ __forceinline__ float ftanh(float x){
  float e = __expf(2.0f*x);
  return 1.0f - 2.0f/(e+1.0f);
}
// pack two fp32 -> two bf16 (truncate) in one v_perm_b32 (lo in low half)
__device__ __forceinline__ unsigned pk(float lo, float hi){
  return __builtin_amdgcn_perm(__float_as_uint(hi), __float_as_uint(lo), 0x07060302u);
}

// ---- convert fc1w[:, 2H:3H] slices (att + pinyin) to bf16 [j][k] ----
__global__ void k_cvt_fc1w(const float* __restrict__ aw, const float* __restrict__ pw,
                           ushort* __restrict__ ab, ushort* __restrict__ pb){
  int tt = blockIdx.x*256 + threadIdx.x;   // 262144 threads
  int idx = tt*8;
  int s = idx >> 20;                        // 0:a 1:p (1048576 elems each)
  int r = idx & 1048575;
  int j = r >> 10, k = r & 1023;
  const float* src = (s? pw : aw) + (size_t)j*3072 + 2048 + k;
  float4 f0 = *(const float4*)src, f1 = *(const float4*)(src+4);
  uint4 p = { pk(f0.x,f0.y), pk(f0.z,f0.w), pk(f1.x,f1.y), pk(f1.z,f1.w) };
  *(uint4*)((s? pb : ab) + r) = p;
}

// x[b][k] = embedding[ids[b]][k]
__global__ void k_embed(const int* __restrict__ ids, const float* __restrict__ emb,
                        float* __restrict__ x){
  int t = blockIdx.x*256 + threadIdx.x;
  int b = t >> 10, k = t & (Hd-1);
  x[t] = emb[(size_t)ids[b]*Hd + k];
}

// 9 gate-sets x split-4 K: g 0-2: x@Wih0, 3-5: hid0@Whh0, 6-8: hid1@Whh1
__global__ void k_gates9(const float* __restrict__ x, const float* __restrict__ hid,
                         const float* __restrict__ Wih0, const float* __restrict__ Whh0,
                         const float* __restrict__ Whh1, float* __restrict__ gA){
  int blk = blockIdx.x;                 // 9*4*128 = 4608
  int g  = blk >> 9;
  int kc = (blk >> 7) & 3;
  int tt = (blk & 127)*256 + threadIdx.x;
  int b = tt & 31, j = tt >> 5;
  const float* vec; const float* w;
  if (g < 3){ vec = x + b*Hd; w = Wih0 + ((size_t)(g*Hd + j))*Hd; }
  else if (g < 6){ vec = hid + b*Hd; w = Whh0 + ((size_t)((g-3)*Hd + j))*Hd; }
  else { vec = hid + Bsz*Hd + b*Hd; w = Whh1 + ((size_t)((g-6)*Hd + j))*Hd; }
  const float4* v4 = (const float4*)(vec + kc*256);
  const float4* w4 = (const float4*)(w + kc*256);
  float acc = 0.f;
  #pragma unroll 8
  for (int k=0;k<64;k++){ float4 a=v4[k], ww=w4[k];
    acc += a.x*ww.x+a.y*ww.y+a.z*ww.z+a.w*ww.w; }
  atomicAdd(&gA[(size_t)g*32768 + j*32 + b], acc);
}

// 3 gate-sets x split-4 K: h0 @ Wih1
__global__ void k_gates3(const float* __restrict__ h0, const float* __restrict__ Wih1,
                         float* __restrict__ gB){
  int blk = blockIdx.x;                 // 3*4*128 = 1536
  int g  = blk >> 9;
  int kc = (blk >> 7) & 3;
  int tt = (blk & 127)*256 + threadIdx.x;
  int b = tt & 31, j = tt >> 5;
  const float4* v4 = (const float4*)(h0 + b*Hd + kc*256);
  const float4* w4 = (const float4*)(Wih1 + ((size_t)(g*Hd + j))*Hd + kc*256);
  float acc = 0.f;
  #pragma unroll 8
  for (int k=0;k<64;k++){ float4 a=v4[k], ww=w4[k];
    acc += a.x*ww.x+a.y*ww.y+a.z*ww.z+a.w*ww.w; }
  atomicAdd(&gB[(size_t)g*32768 + j*32 + b], acc);
}

// combine gates: xg/hg each 3 sets of [j*32+b] sums; h' per torch GRU
__global__ void k_gru_comb(const float* __restrict__ xg, const float* __restrict__ hg,
                           const float* __restrict__ h, const float* __restrict__ bih,
                           const float* __restrict__ bhh, float* __restrict__ hnew){
  int tt = blockIdx.x*256 + threadIdx.x;
  int b = tt & 31, j = tt >> 5;
  float ir = xg[tt], iz = xg[32768 + tt], in_ = xg[2*32768 + tt];
  float hr = hg[tt], hz = hg[32768 + tt], hn  = hg[2*32768 + tt];
  float r = sigf(ir + bih[j]      + hr + bhh[j]);
  float z = sigf(iz + bih[Hd+j]   + hz + bhh[Hd+j]);
  float n = ftanh(in_ + bih[2*Hd+j] + r*(hn + bhh[2*Hd+j]));
  hnew[(size_t)b*Hd + j] = (1.f-z)*n + z*h[(size_t)b*Hd + j];
}

// state projection split: sp[s][b][j] += [h0|h1] . fc1w[j, 0:2H] chunks (no bias)
__global__ void k_spsplit(const float* __restrict__ h0, const float* __restrict__ h1,
                          const float* __restrict__ afc1w, const float* __restrict__ pfc1w,
                          float* __restrict__ spa_, float* __restrict__ spp_){
  int blk = blockIdx.x;                 // 2*4*128 = 1024
  int s  = blk >> 9;
  int kc = (blk >> 7) & 3;
  int tt = (blk & 127)*256 + threadIdx.x;
  int b = tt & 31, j = tt >> 5;
  const float* w = (s? pfc1w : afc1w) + (size_t)j*3*Hd + kc*512;
  const float* vec = (kc < 2 ? h0 : h1) + b*Hd + (kc & 1)*512;
  const float4* v4 = (const float4*)vec;
  const float4* w4 = (const float4*)w;
  float acc = 0.f;
  #pragma unroll 8
  for (int k=0;k<128;k++){ float4 a=v4[k], ww=w4[k];
    acc += a.x*ww.x+a.y*ww.y+a.z*ww.z+a.w*ww.w; }
  atomicAdd((s? spp_ : spa_) + (size_t)b*Hd + j, acc);
}

// fused MFMA attention GEMM + tanh/fc2/row-reduce epilogue. z: att / pinyin.
// XCD-aware remap: flat%8 = XCD (dispatch round-robin); each XCD owns a
// contiguous band of 16 row-tiles x all 8 col-blocks x both z, so the 8
// col-blocks sharing one 512KB A-tile are co-resident on ONE XCD's L2,
// and the 2MB bf16 B-panel stays L2-resident per XCD.
__global__ __launch_bounds__(256, 4)
void k_att_mfma(const float* __restrict__ enc0, const float* __restrict__ enc1,
                const ushort* __restrict__ wb0, const ushort* __restrict__ wb1,
                const float* __restrict__ sp0, const float* __restrict__ sp1,
                const float* __restrict__ b10, const float* __restrict__ b11,
                const float* __restrict__ w20, const float* __restrict__ w21,
                float* __restrict__ e0, float* __restrict__ e1){
  // bijective swizzle over 2048 blocks (nwg % 8 == 0)
  const int flat = blockIdx.x + (blockIdx.y << 3) + (blockIdx.z << 10);
  const int xcd  = flat & 7;
  const int widx = flat >> 3;           // 0..255 work item within XCD
  const int z    = widx >> 7;           // coarse: z=0 band then z=1 band
  const int rem  = widx & 127;
  const int rowt = (xcd << 4) + (rem >> 3);  // 16 row-tiles per XCD
  const int colb = rem & 7;                  // col fastest -> 8 sharers co-resident

  const float*  enc = z? enc1 : enc0;
  const ushort* wb  = z? wb1  : wb0;
  const float*  sp  = z? sp1  : sp0;
  const float*  b1  = z? b11  : b10;
  const float*  fc2 = z? w21  : w20;
  float* e = z? e1 : e0;
  __shared__ __align__(16) ushort As[128*72];   // [row][k], pad 72 (2-way banks)
  __shared__ __align__(16) ushort Bs[128*72];
  const int t = threadIdx.x;
  const int lane = t & 63;
  const int w = t >> 6;
  const int wm = w >> 1, wn = w & 1;
  const int q = lane >> 4, c15 = lane & 15;
  const int row0 = rowt * 128;   // over S*B
  const int col0 = colb * 128;   // over H

  const int lrow = t >> 3, lkp = (t & 7)*8;     // A staging: 32 rows x 8 kparts
  const float* gA = enc + (size_t)(row0 + lrow)*Hd + lkp;
  const int brow = t >> 1, bkp = (t & 1)*32;    // B staging: 128 rows x 2 halves
  const ushort* gB = wb + (size_t)(col0 + brow)*Hd + bkp;

  v4f acc[4][4];
  for (int mi=0;mi<4;mi++) for (int ni=0;ni<4;ni++) acc[mi][ni] = (v4f){0.f,0.f,0.f,0.f};

  for (int k0 = 0; k0 < Hd; k0 += 64){
    #pragma unroll
    for (int i = 0; i < 4; i++){
      const float* p = gA + (size_t)i*32*Hd + k0;
      float4 a0 = *(const float4*)p;
      float4 a1 = *(const float4*)(p+4);
      uint4 pa = { pk(a0.x,a0.y), pk(a0.z,a0.w), pk(a1.x,a1.y), pk(a1.z,a1.w) };
      *(uint4*)&As[(i*32 + lrow)*72 + lkp] = pa;
    }
    {
      const uint4* pb4 = (const uint4*)(gB + k0);
      uint4 b0_=pb4[0], b1_=pb4[1], b2_=pb4[2], b3_=pb4[3];
      uint4* d = (uint4*)&Bs[brow*72 + bkp];
      d[0]=b0_; d[1]=b1_; d[2]=b2_; d[3]=b3_;
    }
    __syncthreads();
    #pragma unroll
    for (int kk = 0; kk < 2; kk++){
      v8s af[4], bf[4];
      #pragma unroll
      for (int mi=0;mi<4;mi++)
        af[mi] = *(const v8s*)&As[(wm*64 + mi*16 + c15)*72 + kk*32 + q*8];
      #pragma unroll
      for (int ni=0;ni<4;ni++)
        bf[ni] = *(const v8s*)&Bs[(wn*64 + ni*16 + c15)*72 + kk*32 + q*8];
      #pragma unroll
      for (int mi=0;mi<4;mi++)
        #pragma unroll
        for (int ni=0;ni<4;ni++)
          acc[mi][ni] = __builtin_amdgcn_mfma_f32_16x16x32_bf16(af[mi], bf[ni], acc[mi][ni], 0, 0, 0);
    }
    __syncthreads();
  }

  // epilogue: e[row] += sum_col fc2[col]*tanh(C + sp[b][col] + fc1b[col])
  #pragma unroll
  for (int mi=0;mi<4;mi++){
    float rs[4] = {0.f,0.f,0.f,0.f};
    #pragma unroll
    for (int ni=0;ni<4;ni++){
      int col = col0 + wn*64 + ni*16 + c15;
      float w2 = fc2[col];
      float bb1 = b1[col];
      int bb = (mi & 1) * 16;
      #pragma unroll
      for (int r=0;r<4;r++){
        int b = bb + q*4 + r;     // global row & 31
        float xv = acc[mi][ni][r] + sp[(size_t)b*Hd + col] + bb1;
        rs[r] += w2 * ftanh(xv);
      }
    }
    #pragma unroll
    for (int r=0;r<4;r++){
      float v = rs[r];
      v += __shfl_xor(v, 1);
      v += __shfl_xor(v, 2);
      v += __shfl_xor(v, 4);
      v += __shfl_xor(v, 8);
      if (c15 == 0)
        atomicAdd(&e[row0 + wm*64 + mi*16 + q*4 + r], v);
    }
  }
}

// in-place softmax over s per b; y-dim selects att/pinyin
__global__ void k_softmax(float* __restrict__ ea_, float* __restrict__ ep_){
  float* e = blockIdx.y ? ep_ : ea_;
  const int b = blockIdx.x, t = threadIdx.x;
  __shared__ float red[256];
  float v1 = e[t*Bsz + b], v2 = e[(t+256)*Bsz + b];
  red[t] = fmaxf(v1, v2);
  __syncthreads();
  for (int off=128; off; off>>=1){ if (t<off) red[t]=fmaxf(red[t],red[t+off]); __syncthreads(); }
  float m = red[0];
  __syncthreads();
  float e1 = __expf(v1-m), e2 = __expf(v2-m);
  red[t] = e1 + e2;
  __syncthreads();
  for (int off=128; off; off>>=1){ if (t<off) red[t]+=red[t+off]; __syncthreads(); }
  float inv = 1.0f/red[0];
  e[t*Bsz + b] = e1*inv;
  e[(t+256)*Bsz + b] = e2*inv;
}

// ctx[b][h] += sum_s alpha[s*B+b]*enc[s][b][h]; grid (B, 8 s-chunks, 2)
__global__ void k_context(const float* __restrict__ ea_, const float* __restrict__ ep_,
                          const float* __restrict__ enc0, const float* __restrict__ enc1,
                          float* __restrict__ ctx0, float* __restrict__ ctx1){
  const int z = blockIdx.z;
  const float* alpha = z? ep_ : ea_;
  const float* enc   = z? enc1 : enc0;
  float* ctx         = z? ctx1 : ctx0;
  const int b = blockIdx.x, c = blockIdx.y, t = threadIdx.x;
  float4 acc = {0,0,0,0};
  for (int s = c*64; s < c*64 + 64; s++){
    float a = alpha[s*Bsz + b];
    float4 ev = *(const float4*)(enc + (size_t)(s*Bsz+b)*Hd + t*4);
    acc.x += a*ev.x; acc.y += a*ev.y; acc.z += a*ev.z; acc.w += a*ev.w;
  }
  float* p = ctx + (size_t)b*Hd + t*4;
  atomicAdd(p+0, acc.x); atomicAdd(p+1, acc.y);
  atomicAdd(p+2, acc.z); atomicAdd(p+3, acc.w);
}

// attnfc split-K (12 chunks of 256 over [h1|ctx|ctxp]) -> o1acc[j*32+b]
__global__ void k_fcsplit(const float* __restrict__ h1, const float* __restrict__ ctx,
                          const float* __restrict__ ctxp, const float* __restrict__ W,
                          float* __restrict__ o1acc){
  int blk = blockIdx.x;                 // 12*128 = 1536
  int c = blk >> 7;
  int tt = (blk & 127)*256 + threadIdx.x;
  int b = tt & 31, j = tt >> 5;
  int seg = c >> 2, off = (c & 3)*256;
  const float* vec = (seg==0 ? h1 : (seg==1 ? ctx : ctxp)) + b*Hd + off;
  const float* w = W + (size_t)j*3*Hd + seg*Hd + off;
  const float4* v4 = (const float4*)vec;
  const float4* w4 = (const float4*)w;
  float acc = 0.f;
  #pragma unroll 8
  for (int k=0;k<64;k++){ float4 a=v4[k], ww=w4[k];
    acc += a.x*ww.x+a.y*ww.y+a.z*ww.z+a.w*ww.w; }
  atomicAdd(&o1acc[(size_t)j*32 + b], acc);
}

// o1b[b][j] = bf16(relu(o1acc + bias))
__global__ void k_o1comb(const float* __restrict__ o1acc, const float* __restrict__ bias,
                         ushort* __restrict__ o1b){
  int tt = blockIdx.x*256 + threadIdx.x;
  int b = tt & 31, j = tt >> 5;
  float acc = fmaxf(o1acc[tt] + bias[j], 0.f);
  o1b[(size_t)b*Hd + j] = (ushort)(__float_as_uint(acc) >> 16);
}

// logits = o1 @ fcw^T + fcb, barrier-free: each wave owns 16 cols, loads its
// B fragment straight from global (fp32->bf16 in-register), A (o1b, 64KB) is
// L1/L2-resident. No LDS, no __syncthreads -> compiler software-pipelines.
// 250 blocks x 512 thr, BN=128. Numerically identical to the LDS version.
__global__ __launch_bounds__(512)
void k_logits(const ushort* __restrict__ o1b, const float* __restrict__ fcw,
              const float* __restrict__ fcb, float* __restrict__ lg){
  const int t = threadIdx.x;
  const int lane = t & 63, w = t >> 6;   // 8 waves, wave w -> 16 cols
  const int q = lane >> 4, c15 = lane & 15;
  const int v0 = blockIdx.x * 128;
  const int col = v0 + w*16 + c15;
  const float*  gB  = fcw + (size_t)col*Hd + q*8;
  const ushort* gA0 = o1b + (size_t)c15*Hd + q*8;
  const ushort* gA1 = o1b + (size_t)(16 + c15)*Hd + q*8;
  v4f acc[2] = {(v4f){0,0,0,0},(v4f){0,0,0,0}};
  #pragma unroll 4
  for (int k=0;k<Hd;k+=32){
    float4 f0 = *(const float4*)(gB + k);
    float4 f1 = *(const float4*)(gB + k + 4);
    uint4 p = { pk(f0.x,f0.y), pk(f0.z,f0.w), pk(f1.x,f1.y), pk(f1.z,f1.w) };
    v8s bfrag = *(const v8s*)&p;
    v8s a0 = *(const v8s*)(gA0 + k);
    v8s a1 = *(const v8s*)(gA1 + k);
    acc[0] = __builtin_amdgcn_mfma_f32_16x16x32_bf16(a0, bfrag, acc[0], 0, 0, 0);
    acc[1] = __builtin_amdgcn_mfma_f32_16x16x32_bf16(a1, bfrag, acc[1], 0, 0, 0);
  }
  float bias = fcb[col];
  #pragma unroll
  for (int mf=0;mf<2;mf++)
    #pragma unroll
    for (int r=0;r<4;r++){
      int b = mf*16 + q*4 + r;
      lg[(size_t)b*Vd + col] = acc[mf][r] + bias;
    }
}

extern "C" void kernel_launch(void* const* d_in, const int* in_sizes, int n_in,
                              void* d_out, int out_size, void* d_ws, size_t ws_size,
                              hipStream_t stream) {
  const int*   ids  = (const int*)  d_in[0];
  const float* hid  = (const float*)d_in[1];
  const float* enc  = (const float*)d_in[2];
  const float* encp = (const float*)d_in[3];
  const float* emb  = (const float*)d_in[4];
  const float* Wih0 = (const float*)d_in[5];
  const float* Whh0 = (const float*)d_in[6];
  const float* bih0 = (const float*)d_in[7];
  const float* bhh0 = (const float*)d_in[8];
  const float* Wih1 = (const float*)d_in[9];
  const float* Whh1 = (const float*)d_in[10];
  const float* bih1 = (const float*)d_in[11];
  const float* bhh1 = (const float*)d_in[12];
  const float* afc1w= (const float*)d_in[13];
  const float* afc1b= (const float*)d_in[14];
  const float* afc2w= (const float*)d_in[15];
  /* d_in[16] att_fc2_b: softmax-invariant -> unused */
  const float* pfc1w= (const float*)d_in[17];
  const float* pfc1b= (const float*)d_in[18];
  const float* pfc2w= (const float*)d_in[19];
  /* d_in[20] attp_fc2_b unused */
  const float* nfcw = (const float*)d_in[21];
  const float* nfcb = (const float*)d_in[22];
  const float* fcw  = (const float*)d_in[23];
  const float* fcb  = (const float*)d_in[24];

  float* outp   = (float*)d_out;
  float* logits = outp;                          // [B,V]
  float* h0     = outp + (size_t)Bsz*Vd;         // new_hidden[0]
  float* h1     = h0 + Bsz*Hd;                   // new_hidden[1]

  float* ws = (float*)d_ws;
  ushort* fc1wab = (ushort*)ws;                       // 1048576 ushorts
  ushort* fc1wpb = (ushort*)(ws + 524288);
  float* x    = ws + 1048576;                         // 32768
  float* spa  = ws + 1081344;                         // 32768  (zeroed)
  float* spp  = ws + 1114112;                         // 32768  (zeroed)
  float* ea   = ws + 1146880;                         // 16384  (zeroed)
  float* ep   = ws + 1163264;                         // 16384  (zeroed)
  float* ctx  = ws + 1179648;                         // 32768  (zeroed)
  float* ctxp = ws + 1212416;                         // 32768  (zeroed)
  float* gA   = ws + 1245184;                         // 294912 (zeroed)
  float* gB   = ws + 1540096;                         // 98304  (zeroed)
  float* o1a  = ws + 1638400;                         // 32768  (zeroed)
  ushort* o1b = (ushort*)(ws + 1671168);              // 32768 ushorts

  // zero all atomic-accumulated buffers: spa..o1a contiguous
  hipMemsetAsync(spa, 0, (size_t)589824*sizeof(float), stream);

  k_cvt_fc1w<<<1024, 256, 0, stream>>>(afc1w, pfc1w, fc1wab, fc1wpb);
  k_embed   <<<Bsz*Hd/256, 256, 0, stream>>>(ids, emb, x);
  k_gates9  <<<4608, 256, 0, stream>>>(x, hid, Wih0, Whh0, Whh1, gA);
  k_gru_comb<<<128, 256, 0, stream>>>(gA, gA + 3*32768, hid, bih0, bhh0, h0);
  k_gates3  <<<1536, 256, 0, stream>>>(h0, Wih1, gB);
  k_gru_comb<<<128, 256, 0, stream>>>(gB, gA + 6*32768, hid + Bsz*Hd, bih1, bhh1, h1);
  k_spsplit <<<1024, 256, 0, stream>>>(h0, h1, afc1w, pfc1w, spa, spp);

  dim3 ga(Hd/128, Sd*Bsz/128, 2);   // (8, 128, 2)
  k_att_mfma<<<ga, 256, 0, stream>>>(enc, encp, fc1wab, fc1wpb, spa, spp,
                                     afc1b, pfc1b, afc2w, pfc2w, ea, ep);

  k_softmax<<<dim3(Bsz,2), 256, 0, stream>>>(ea, ep);
  k_context<<<dim3(Bsz,8,2), 256, 0, stream>>>(ea, ep, enc, encp, ctx, ctxp);

  k_fcsplit<<<1536, 256, 0, stream>>>(h1, ctx, ctxp, nfcw, o1a);
  k_o1comb <<<128, 256, 0, stream>>>(o1a, nfcb, o1b);
  k_logits <<<Vd/128, 512, 0, stream>>>(o1b, fcw, fcb, logits);
}

// Round 2
// 898.013 us; speedup vs baseline: 1.0151x; 1.0151x over previous
//
#include <hip/hip_runtime.h>
#include <math.h>

#define Bsz 32
#define Hd  1024
#define Sd  512
#define Vd  32000

typedef __attribute__((ext_vector_type(8))) short v8s;
typedef __attribute__((ext_vector_type(4))) float v4f;

typedef __attribute__((address_space(1))) const unsigned int AS1c;
typedef __attribute__((address_space(3))) unsigned int AS3u;

__device__ __forceinline__ void gload16(const void* g, const ushort* l){
  __builtin_amdgcn_global_load_lds((AS1c*)g, (AS3u*)l, 16, 0, 0);
}

__device__ __forceinline__ float sigf(float x){ return 1.0f/(1.0f+__expf(-x)); }
__device__ __forceinline__ float ftanh(float x){
  float e = __expf(2.0f*x);
  return 1.0f - 2.0f/(e+1.0f);
}
// pack two fp32 -> two bf16 (truncate) in one v_perm_b32 (lo in low half)
__device__ __forceinline__ unsigned pk(float lo, float hi){
  return __builtin_amdgcn_perm(__float_as_uint(hi), __float_as_uint(lo), 0x07060302u);
}

// ============ NEW-PATH conversion kernels: tiled + XOR-swizzled bf16 ============
// Tile scheme (shared by A and B): matrix [R][1024] bf16 -> tiles (rt = r>>7,
// kt = k>>6), tile base = (rt*16+kt)*8192 ushorts; element (r,k) at ushort
// rl*64 + ((k&63) ^ ((rl&7)<<3)), rl = r&127.  global_load_lds then copies the
// tile LINEARLY into LDS and the MFMA ds_reads apply the same XOR -> conflict-free.

// fc1w[:, 2H:3H] slices (att + pinyin) -> tiled bf16
__global__ void k_cvt_fc1w_t(const float* __restrict__ aw, const float* __restrict__ pw,
                             ushort* __restrict__ ab, ushort* __restrict__ pb){
  int tt = blockIdx.x*256 + threadIdx.x;   // 262144 threads: 2 x 1024 cols x 128 kgroups
  int s = tt >> 17;
  int j = (tt >> 7) & 1023;                // col
  int g = tt & 127;                        // k-group of 8
  const float* src = (s? pw : aw) + (size_t)j*3072 + 2048 + g*8;
  float4 f0 = *(const float4*)src, f1 = *(const float4*)(src+4);
  uint4 p = { pk(f0.x,f0.y), pk(f0.z,f0.w), pk(f1.x,f1.y), pk(f1.z,f1.w) };
  int ct = j >> 7, cl = j & 127, kt = g >> 3, gl = g & 7;
  size_t off = ((size_t)(ct*16 + kt))*8192 + (size_t)cl*64 + (((gl*8) ^ ((cl&7)<<3)));
  *(uint4*)((s? pb : ab) + off) = p;
}

// enc / encp fp32 [16384][1024] -> tiled bf16
__global__ void k_cvt_enc(const float* __restrict__ e0, const float* __restrict__ e1,
                          ushort* __restrict__ o0, ushort* __restrict__ o1){
  int tt = blockIdx.x*256 + threadIdx.x;   // 4194304 threads: 2 x 16384 rows x 128 kgroups
  int z = tt >> 21;
  int r = (tt >> 7) & 16383;
  int g = tt & 127;
  const float* src = (z? e1 : e0) + (size_t)r*1024 + g*8;
  float4 f0 = *(const float4*)src, f1 = *(const float4*)(src+4);
  uint4 p = { pk(f0.x,f0.y), pk(f0.z,f0.w), pk(f1.x,f1.y), pk(f1.z,f1.w) };
  int rt = r >> 7, rl = r & 127, kt = g >> 3, gl = g & 7;
  size_t off = ((size_t)(rt*16 + kt))*8192 + (size_t)rl*64 + (((gl*8) ^ ((rl&7)<<3)));
  *(uint4*)((z? o1 : o0) + off) = p;
}

// ============ old-path conversion (fallback, row-major [j][k] bf16) ============
__global__ void k_cvt_fc1w(const float* __restrict__ aw, const float* __restrict__ pw,
                           ushort* __restrict__ ab, ushort* __restrict__ pb){
  int tt = blockIdx.x*256 + threadIdx.x;
  int idx = tt*8;
  int s = idx >> 20;
  int r = idx & 1048575;
  int j = r >> 10, k = r & 1023;
  const float* src = (s? pw : aw) + (size_t)j*3072 + 2048 + k;
  float4 f0 = *(const float4*)src, f1 = *(const float4*)(src+4);
  uint4 p = { pk(f0.x,f0.y), pk(f0.z,f0.w), pk(f1.x,f1.y), pk(f1.z,f1.w) };
  *(uint4*)((s? pb : ab) + r) = p;
}

// 9 gate-sets x split-4 K (embed fused: g<3 reads emb[ids[b]] directly)
__global__ void k_gates9(const int* __restrict__ ids, const float* __restrict__ emb,
                         const float* __restrict__ hid,
                         const float* __restrict__ Wih0, const float* __restrict__ Whh0,
                         const float* __restrict__ Whh1, float* __restrict__ gA){
  int blk = blockIdx.x;                 // 9*4*128 = 4608
  int g  = blk >> 9;
  int kc = (blk >> 7) & 3;
  int tt = (blk & 127)*256 + threadIdx.x;
  int b = tt & 31, j = tt >> 5;
  const float* vec; const float* w;
  if (g < 3){ vec = emb + (size_t)ids[b]*Hd; w = Wih0 + ((size_t)(g*Hd + j))*Hd; }
  else if (g < 6){ vec = hid + b*Hd; w = Whh0 + ((size_t)((g-3)*Hd + j))*Hd; }
  else { vec = hid + Bsz*Hd + b*Hd; w = Whh1 + ((size_t)((g-6)*Hd + j))*Hd; }
  const float4* v4 = (const float4*)(vec + kc*256);
  const float4* w4 = (const float4*)(w + kc*256);
  float acc = 0.f;
  #pragma unroll 8
  for (int k=0;k<64;k++){ float4 a=v4[k], ww=w4[k];
    acc += a.x*ww.x+a.y*ww.y+a.z*ww.z+a.w*ww.w; }
  atomicAdd(&gA[(size_t)g*32768 + j*32 + b], acc);
}

// 3 gate-sets x split-4 K: h0 @ Wih1
__global__ void k_gates3(const float* __restrict__ h0, const float* __restrict__ Wih1,
                         float* __restrict__ gB){
  int blk = blockIdx.x;                 // 3*4*128 = 1536
  int g  = blk >> 9;
  int kc = (blk >> 7) & 3;
  int tt = (blk & 127)*256 + threadIdx.x;
  int b = tt & 31, j = tt >> 5;
  const float4* v4 = (const float4*)(h0 + b*Hd + kc*256);
  const float4* w4 = (const float4*)(Wih1 + ((size_t)(g*Hd + j))*Hd + kc*256);
  float acc = 0.f;
  #pragma unroll 8
  for (int k=0;k<64;k++){ float4 a=v4[k], ww=w4[k];
    acc += a.x*ww.x+a.y*ww.y+a.z*ww.z+a.w*ww.w; }
  atomicAdd(&gB[(size_t)g*32768 + j*32 + b], acc);
}

// combine gates: xg/hg each 3 sets of [j*32+b] sums; h' per torch GRU
__global__ void k_gru_comb(const float* __restrict__ xg, const float* __restrict__ hg,
                           const float* __restrict__ h, const float* __restrict__ bih,
                           const float* __restrict__ bhh, float* __restrict__ hnew){
  int tt = blockIdx.x*256 + threadIdx.x;
  int b = tt & 31, j = tt >> 5;
  float ir = xg[tt], iz = xg[32768 + tt], in_ = xg[2*32768 + tt];
  float hr = hg[tt], hz = hg[32768 + tt], hn  = hg[2*32768 + tt];
  float r = sigf(ir + bih[j]      + hr + bhh[j]);
  float z = sigf(iz + bih[Hd+j]   + hz + bhh[Hd+j]);
  float n = ftanh(in_ + bih[2*Hd+j] + r*(hn + bhh[2*Hd+j]));
  hnew[(size_t)b*Hd + j] = (1.f-z)*n + z*h[(size_t)b*Hd + j];
}

// state projection split: sp[s][b][j] += [h0|h1] . fc1w[j, 0:2H] chunks (no bias)
__global__ void k_spsplit(const float* __restrict__ h0, const float* __restrict__ h1,
                          const float* __restrict__ afc1w, const float* __restrict__ pfc1w,
                          float* __restrict__ spa_, float* __restrict__ spp_){
  int blk = blockIdx.x;                 // 2*4*128 = 1024
  int s  = blk >> 9;
  int kc = (blk >> 7) & 3;
  int tt = (blk & 127)*256 + threadIdx.x;
  int b = tt & 31, j = tt >> 5;
  const float* w = (s? pfc1w : afc1w) + (size_t)j*3*Hd + kc*512;
  const float* vec = (kc < 2 ? h0 : h1) + b*Hd + (kc & 1)*512;
  const float4* v4 = (const float4*)vec;
  const float4* w4 = (const float4*)w;
  float acc = 0.f;
  #pragma unroll 8
  for (int k=0;k<128;k++){ float4 a=v4[k], ww=w4[k];
    acc += a.x*ww.x+a.y*ww.y+a.z*ww.z+a.w*ww.w; }
  atomicAdd((s? spp_ : spa_) + (size_t)b*Hd + j, acc);
}

// ======== NEW k_att: global_load_lds staging from pre-tiled bf16 operands ========
// Per K-step: 4+4 contiguous 4KB global_load_lds issues (no VALU pack, no
// ds_write, no VGPR round-trip), then 16 swizzled ds_read_b128 + 32 MFMA.
// XOR swizzle baked into the tile layout (cvt kernels) and applied on reads.
__global__ __launch_bounds__(256, 4)
void k_att_mfma2(const ushort* __restrict__ eb0, const ushort* __restrict__ eb1,
                 const ushort* __restrict__ wb0, const ushort* __restrict__ wb1,
                 const float* __restrict__ sp0, const float* __restrict__ sp1,
                 const float* __restrict__ b10, const float* __restrict__ b11,
                 const float* __restrict__ w20, const float* __restrict__ w21,
                 float* __restrict__ e0, float* __restrict__ e1){
  // bijective XCD swizzle over 2048 blocks
  const int flat = blockIdx.x + (blockIdx.y << 3) + (blockIdx.z << 10);
  const int xcd  = flat & 7;
  const int widx = flat >> 3;
  const int z    = widx >> 7;
  const int rem  = widx & 127;
  const int rowt = (xcd << 4) + (rem >> 3);
  const int colb = rem & 7;

  const ushort* eb = z? eb1 : eb0;
  const ushort* wb = z? wb1 : wb0;
  const float*  sp = z? sp1 : sp0;
  const float*  b1 = z? b11 : b10;
  const float*  fc2= z? w21 : w20;
  float* e = z? e1 : e0;

  __shared__ __align__(16) ushort As[128*64];
  __shared__ __align__(16) ushort Bs[128*64];
  const int t = threadIdx.x;
  const int lane = t & 63;
  const int w = t >> 6;
  const int wm = w >> 1, wn = w & 1;
  const int q = lane >> 4, c15 = lane & 15;
  const int row0 = rowt * 128;
  const int col0 = colb * 128;
  const int rdk  = (c15 & 7) << 3;      // ushort-unit XOR key for frag reads

  // per-lane global source: contiguous within each 16KB tile
  const char* gAk = (const char*)(eb + (size_t)rowt*131072) + w*1024 + lane*16;
  const char* gBk = (const char*)(wb + (size_t)colb*131072) + w*1024 + lane*16;

  v4f acc[4][4];
  #pragma unroll
  for (int mi=0;mi<4;mi++)
    #pragma unroll
    for (int ni=0;ni<4;ni++) acc[mi][ni] = (v4f){0.f,0.f,0.f,0.f};

  for (int kt = 0; kt < 16; kt++){
    #pragma unroll
    for (int j = 0; j < 4; j++){
      gload16(gAk + j*4096, &As[j*2048 + w*512]);
      gload16(gBk + j*4096, &Bs[j*2048 + w*512]);
    }
    __syncthreads();                      // compiler emits vmcnt(0) drain here
    #pragma unroll
    for (int kk = 0; kk < 2; kk++){
      v8s af[4], bf[4];
      #pragma unroll
      for (int mi=0;mi<4;mi++)
        af[mi] = *(const v8s*)&As[(wm*64 + mi*16 + c15)*64 + ((kk*32 + q*8) ^ rdk)];
      #pragma unroll
      for (int ni=0;ni<4;ni++)
        bf[ni] = *(const v8s*)&Bs[(wn*64 + ni*16 + c15)*64 + ((kk*32 + q*8) ^ rdk)];
      #pragma unroll
      for (int mi=0;mi<4;mi++)
        #pragma unroll
        for (int ni=0;ni<4;ni++)
          acc[mi][ni] = __builtin_amdgcn_mfma_f32_16x16x32_bf16(af[mi], bf[ni], acc[mi][ni], 0, 0, 0);
    }
    __syncthreads();
    gAk += 16384; gBk += 16384;
  }

  // epilogue: e[row] += sum_col fc2[col]*tanh(C + sp[b][col] + fc1b[col])
  #pragma unroll
  for (int mi=0;mi<4;mi++){
    float rs[4] = {0.f,0.f,0.f,0.f};
    #pragma unroll
    for (int ni=0;ni<4;ni++){
      int col = col0 + wn*64 + ni*16 + c15;
      float w2 = fc2[col];
      float bb1 = b1[col];
      int bb = (mi & 1) * 16;
      #pragma unroll
      for (int r=0;r<4;r++){
        int b = bb + q*4 + r;
        float xv = acc[mi][ni][r] + sp[(size_t)b*Hd + col] + bb1;
        rs[r] += w2 * ftanh(xv);
      }
    }
    #pragma unroll
    for (int r=0;r<4;r++){
      float v = rs[r];
      v += __shfl_xor(v, 1);
      v += __shfl_xor(v, 2);
      v += __shfl_xor(v, 4);
      v += __shfl_xor(v, 8);
      if (c15 == 0)
        atomicAdd(&e[row0 + wm*64 + mi*16 + q*4 + r], v);
    }
  }
}

// ======== OLD k_att (fallback when workspace too small for enc-bf16) ========
__global__ __launch_bounds__(256, 4)
void k_att_mfma(const float* __restrict__ enc0, const float* __restrict__ enc1,
                const ushort* __restrict__ wb0, const ushort* __restrict__ wb1,
                const float* __restrict__ sp0, const float* __restrict__ sp1,
                const float* __restrict__ b10, const float* __restrict__ b11,
                const float* __restrict__ w20, const float* __restrict__ w21,
                float* __restrict__ e0, float* __restrict__ e1){
  const int flat = blockIdx.x + (blockIdx.y << 3) + (blockIdx.z << 10);
  const int xcd  = flat & 7;
  const int widx = flat >> 3;
  const int z    = widx >> 7;
  const int rem  = widx & 127;
  const int rowt = (xcd << 4) + (rem >> 3);
  const int colb = rem & 7;

  const float*  enc = z? enc1 : enc0;
  const ushort* wb  = z? wb1  : wb0;
  const float*  sp  = z? sp1  : sp0;
  const float*  b1  = z? b11  : b10;
  const float*  fc2 = z? w21  : w20;
  float* e = z? e1 : e0;
  __shared__ __align__(16) ushort As[128*72];
  __shared__ __align__(16) ushort Bs[128*72];
  const int t = threadIdx.x;
  const int lane = t & 63;
  const int w = t >> 6;
  const int wm = w >> 1, wn = w & 1;
  const int q = lane >> 4, c15 = lane & 15;
  const int row0 = rowt * 128;
  const int col0 = colb * 128;

  const int lrow = t >> 3, lkp = (t & 7)*8;
  const float* gA = enc + (size_t)(row0 + lrow)*Hd + lkp;
  const int brow = t >> 1, bkp = (t & 1)*32;
  const ushort* gB = wb + (size_t)(col0 + brow)*Hd + bkp;

  v4f acc[4][4];
  for (int mi=0;mi<4;mi++) for (int ni=0;ni<4;ni++) acc[mi][ni] = (v4f){0.f,0.f,0.f,0.f};

  for (int k0 = 0; k0 < Hd; k0 += 64){
    #pragma unroll
    for (int i = 0; i < 4; i++){
      const float* p = gA + (size_t)i*32*Hd + k0;
      float4 a0 = *(const float4*)p;
      float4 a1 = *(const float4*)(p+4);
      uint4 pa = { pk(a0.x,a0.y), pk(a0.z,a0.w), pk(a1.x,a1.y), pk(a1.z,a1.w) };
      *(uint4*)&As[(i*32 + lrow)*72 + lkp] = pa;
    }
    {
      const uint4* pb4 = (const uint4*)(gB + k0);
      uint4 b0_=pb4[0], b1_=pb4[1], b2_=pb4[2], b3_=pb4[3];
      uint4* d = (uint4*)&Bs[brow*72 + bkp];
      d[0]=b0_; d[1]=b1_; d[2]=b2_; d[3]=b3_;
    }
    __syncthreads();
    #pragma unroll
    for (int kk = 0; kk < 2; kk++){
      v8s af[4], bf[4];
      #pragma unroll
      for (int mi=0;mi<4;mi++)
        af[mi] = *(const v8s*)&As[(wm*64 + mi*16 + c15)*72 + kk*32 + q*8];
      #pragma unroll
      for (int ni=0;ni<4;ni++)
        bf[ni] = *(const v8s*)&Bs[(wn*64 + ni*16 + c15)*72 + kk*32 + q*8];
      #pragma unroll
      for (int mi=0;mi<4;mi++)
        #pragma unroll
        for (int ni=0;ni<4;ni++)
          acc[mi][ni] = __builtin_amdgcn_mfma_f32_16x16x32_bf16(af[mi], bf[ni], acc[mi][ni], 0, 0, 0);
    }
    __syncthreads();
  }

  #pragma unroll
  for (int mi=0;mi<4;mi++){
    float rs[4] = {0.f,0.f,0.f,0.f};
    #pragma unroll
    for (int ni=0;ni<4;ni++){
      int col = col0 + wn*64 + ni*16 + c15;
      float w2 = fc2[col];
      float bb1 = b1[col];
      int bb = (mi & 1) * 16;
      #pragma unroll
      for (int r=0;r<4;r++){
        int b = bb + q*4 + r;
        float xv = acc[mi][ni][r] + sp[(size_t)b*Hd + col] + bb1;
        rs[r] += w2 * ftanh(xv);
      }
    }
    #pragma unroll
    for (int r=0;r<4;r++){
      float v = rs[r];
      v += __shfl_xor(v, 1);
      v += __shfl_xor(v, 2);
      v += __shfl_xor(v, 4);
      v += __shfl_xor(v, 8);
      if (c15 == 0)
        atomicAdd(&e[row0 + wm*64 + mi*16 + q*4 + r], v);
    }
  }
}

// in-place softmax over s per b; y-dim selects att/pinyin
__global__ void k_softmax(float* __restrict__ ea_, float* __restrict__ ep_){
  float* e = blockIdx.y ? ep_ : ea_;
  const int b = blockIdx.x, t = threadIdx.x;
  __shared__ float red[256];
  float v1 = e[t*Bsz + b], v2 = e[(t+256)*Bsz + b];
  red[t] = fmaxf(v1, v2);
  __syncthreads();
  for (int off=128; off; off>>=1){ if (t<off) red[t]=fmaxf(red[t],red[t+off]); __syncthreads(); }
  float m = red[0];
  __syncthreads();
  float e1 = __expf(v1-m), e2 = __expf(v2-m);
  red[t] = e1 + e2;
  __syncthreads();
  for (int off=128; off; off>>=1){ if (t<off) red[t]+=red[t+off]; __syncthreads(); }
  float inv = 1.0f/red[0];
  e[t*Bsz + b] = e1*inv;
  e[(t+256)*Bsz + b] = e2*inv;
}

// ctx[b][h] += sum_s alpha[s*B+b]*enc[s][b][h]; grid (B, 32 s-chunks, 2)
__global__ void k_context(const float* __restrict__ ea_, const float* __restrict__ ep_,
                          const float* __restrict__ enc0, const float* __restrict__ enc1,
                          float* __restrict__ ctx0, float* __restrict__ ctx1){
  const int z = blockIdx.z;
  const float* alpha = z? ep_ : ea_;
  const float* enc   = z? enc1 : enc0;
  float* ctx         = z? ctx1 : ctx0;
  const int b = blockIdx.x, c = blockIdx.y, t = threadIdx.x;
  float4 acc = {0,0,0,0};
  #pragma unroll
  for (int i = 0; i < 16; i++){
    int s = c*16 + i;
    float a = alpha[s*Bsz + b];
    float4 ev = *(const float4*)(enc + (size_t)(s*Bsz+b)*Hd + t*4);
    acc.x += a*ev.x; acc.y += a*ev.y; acc.z += a*ev.z; acc.w += a*ev.w;
  }
  float* p = ctx + (size_t)b*Hd + t*4;
  atomicAdd(p+0, acc.x); atomicAdd(p+1, acc.y);
  atomicAdd(p+2, acc.z); atomicAdd(p+3, acc.w);
}

// attnfc split-K (12 chunks of 256 over [h1|ctx|ctxp]) -> o1acc[j*32+b]
__global__ void k_fcsplit(const float* __restrict__ h1, const float* __restrict__ ctx,
                          const float* __restrict__ ctxp, const float* __restrict__ W,
                          float* __restrict__ o1acc){
  int blk = blockIdx.x;                 // 12*128 = 1536
  int c = blk >> 7;
  int tt = (blk & 127)*256 + threadIdx.x;
  int b = tt & 31, j = tt >> 5;
  int seg = c >> 2, off = (c & 3)*256;
  const float* vec = (seg==0 ? h1 : (seg==1 ? ctx : ctxp)) + b*Hd + off;
  const float* w = W + (size_t)j*3*Hd + seg*Hd + off;
  const float4* v4 = (const float4*)vec;
  const float4* w4 = (const float4*)w;
  float acc = 0.f;
  #pragma unroll 8
  for (int k=0;k<64;k++){ float4 a=v4[k], ww=w4[k];
    acc += a.x*ww.x+a.y*ww.y+a.z*ww.z+a.w*ww.w; }
  atomicAdd(&o1acc[(size_t)j*32 + b], acc);
}

// o1b[b][j] = bf16(relu(o1acc + bias))
__global__ void k_o1comb(const float* __restrict__ o1acc, const float* __restrict__ bias,
                         ushort* __restrict__ o1b){
  int tt = blockIdx.x*256 + threadIdx.x;
  int b = tt & 31, j = tt >> 5;
  float acc = fmaxf(o1acc[tt] + bias[j], 0.f);
  o1b[(size_t)b*Hd + j] = (ushort)(__float_as_uint(acc) >> 16);
}

// logits = o1 @ fcw^T + fcb, barrier-free streaming MFMA
__global__ __launch_bounds__(512)
void k_logits(const ushort* __restrict__ o1b, const float* __restrict__ fcw,
              const float* __restrict__ fcb, float* __restrict__ lg){
  const int t = threadIdx.x;
  const int lane = t & 63, w = t >> 6;
  const int q = lane >> 4, c15 = lane & 15;
  const int v0 = blockIdx.x * 128;
  const int col = v0 + w*16 + c15;
  const float*  gB  = fcw + (size_t)col*Hd + q*8;
  const ushort* gA0 = o1b + (size_t)c15*Hd + q*8;
  const ushort* gA1 = o1b + (size_t)(16 + c15)*Hd + q*8;
  v4f acc[2] = {(v4f){0,0,0,0},(v4f){0,0,0,0}};
  #pragma unroll 8
  for (int k=0;k<Hd;k+=32){
    float4 f0 = *(const float4*)(gB + k);
    float4 f1 = *(const float4*)(gB + k + 4);
    uint4 p = { pk(f0.x,f0.y), pk(f0.z,f0.w), pk(f1.x,f1.y), pk(f1.z,f1.w) };
    v8s bfrag = *(const v8s*)&p;
    v8s a0 = *(const v8s*)(gA0 + k);
    v8s a1 = *(const v8s*)(gA1 + k);
    acc[0] = __builtin_amdgcn_mfma_f32_16x16x32_bf16(a0, bfrag, acc[0], 0, 0, 0);
    acc[1] = __builtin_amdgcn_mfma_f32_16x16x32_bf16(a1, bfrag, acc[1], 0, 0, 0);
  }
  float bias = fcb[col];
  #pragma unroll
  for (int mf=0;mf<2;mf++)
    #pragma unroll
    for (int r=0;r<4;r++){
      int b = mf*16 + q*4 + r;
      lg[(size_t)b*Vd + col] = acc[mf][r] + bias;
    }
}

extern "C" void kernel_launch(void* const* d_in, const int* in_sizes, int n_in,
                              void* d_out, int out_size, void* d_ws, size_t ws_size,
                              hipStream_t stream) {
  const int*   ids  = (const int*)  d_in[0];
  const float* hid  = (const float*)d_in[1];
  const float* enc  = (const float*)d_in[2];
  const float* encp = (const float*)d_in[3];
  const float* emb  = (const float*)d_in[4];
  const float* Wih0 = (const float*)d_in[5];
  const float* Whh0 = (const float*)d_in[6];
  const float* bih0 = (const float*)d_in[7];
  const float* bhh0 = (const float*)d_in[8];
  const float* Wih1 = (const float*)d_in[9];
  const float* Whh1 = (const float*)d_in[10];
  const float* bih1 = (const float*)d_in[11];
  const float* bhh1 = (const float*)d_in[12];
  const float* afc1w= (const float*)d_in[13];
  const float* afc1b= (const float*)d_in[14];
  const float* afc2w= (const float*)d_in[15];
  const float* pfc1w= (const float*)d_in[17];
  const float* pfc1b= (const float*)d_in[18];
  const float* pfc2w= (const float*)d_in[19];
  const float* nfcw = (const float*)d_in[21];
  const float* nfcb = (const float*)d_in[22];
  const float* fcw  = (const float*)d_in[23];
  const float* fcb  = (const float*)d_in[24];

  float* outp   = (float*)d_out;
  float* logits = outp;                          // [B,V]
  float* h0     = outp + (size_t)Bsz*Vd;         // new_hidden[0]
  float* h1     = h0 + Bsz*Hd;                   // new_hidden[1]

  float* ws = (float*)d_ws;
  const size_t NEED = (size_t)(17825792 + 589824 + 16384) * 4;   // ~70.3 MB

  if (ws_size >= NEED){
    // ---- new path: tiled bf16 operands + global_load_lds att ----
    ushort* fc1wab = (ushort*)ws;                   // ushort[1048576]
    ushort* fc1wpb = (ushort*)(ws + 524288);
    ushort* eb0    = (ushort*)(ws + 1048576);       // ushort[16777216]
    ushort* eb1    = (ushort*)(ws + 9437184);
    float* spa  = ws + 17825792;                    // zero region start
    float* spp  = spa + 32768;
    float* ea   = spa + 65536;
    float* ep   = spa + 81920;
    float* ctx  = spa + 98304;
    float* ctxp = spa + 131072;
    float* gA   = spa + 163840;
    float* gB   = spa + 458752;
    float* o1a  = spa + 557056;
    ushort* o1b = (ushort*)(spa + 589824);

    hipMemsetAsync(spa, 0, (size_t)589824*sizeof(float), stream);

    k_cvt_fc1w_t<<<1024, 256, 0, stream>>>(afc1w, pfc1w, fc1wab, fc1wpb);
    k_cvt_enc   <<<16384, 256, 0, stream>>>(enc, encp, eb0, eb1);
    k_gates9    <<<4608, 256, 0, stream>>>(ids, emb, hid, Wih0, Whh0, Whh1, gA);
    k_gru_comb  <<<128, 256, 0, stream>>>(gA, gA + 3*32768, hid, bih0, bhh0, h0);
    k_gates3    <<<1536, 256, 0, stream>>>(h0, Wih1, gB);
    k_gru_comb  <<<128, 256, 0, stream>>>(gB, gA + 6*32768, hid + Bsz*Hd, bih1, bhh1, h1);
    k_spsplit   <<<1024, 256, 0, stream>>>(h0, h1, afc1w, pfc1w, spa, spp);

    dim3 ga(Hd/128, Sd*Bsz/128, 2);   // (8, 128, 2)
    k_att_mfma2<<<ga, 256, 0, stream>>>(eb0, eb1, fc1wab, fc1wpb, spa, spp,
                                        afc1b, pfc1b, afc2w, pfc2w, ea, ep);

    k_softmax<<<dim3(Bsz,2), 256, 0, stream>>>(ea, ep);
    k_context<<<dim3(Bsz,32,2), 256, 0, stream>>>(ea, ep, enc, encp, ctx, ctxp);

    k_fcsplit<<<1536, 256, 0, stream>>>(h1, ctx, ctxp, nfcw, o1a);
    k_o1comb <<<128, 256, 0, stream>>>(o1a, nfcb, o1b);
    k_logits <<<Vd/128, 512, 0, stream>>>(o1b, fcw, fcb, logits);
  } else {
    // ---- fallback: round-1 layout (fp32 A staged in-kernel) ----
    ushort* fc1wab = (ushort*)ws;
    ushort* fc1wpb = (ushort*)(ws + 524288);
    float* spa  = ws + 1081344;
    float* spp  = ws + 1114112;
    float* ea   = ws + 1146880;
    float* ep   = ws + 1163264;
    float* ctx  = ws + 1179648;
    float* ctxp = ws + 1212416;
    float* gA   = ws + 1245184;
    float* gB   = ws + 1540096;
    float* o1a  = ws + 1638400;
    ushort* o1b = (ushort*)(ws + 1671168);

    hipMemsetAsync(spa, 0, (size_t)589824*sizeof(float), stream);

    k_cvt_fc1w<<<1024, 256, 0, stream>>>(afc1w, pfc1w, fc1wab, fc1wpb);
    k_gates9  <<<4608, 256, 0, stream>>>(ids, emb, hid, Wih0, Whh0, Whh1, gA);
    k_gru_comb<<<128, 256, 0, stream>>>(gA, gA + 3*32768, hid, bih0, bhh0, h0);
    k_gates3  <<<1536, 256, 0, stream>>>(h0, Wih1, gB);
    k_gru_comb<<<128, 256, 0, stream>>>(gB, gA + 6*32768, hid + Bsz*Hd, bih1, bhh1, h1);
    k_spsplit <<<1024, 256, 0, stream>>>(h0, h1, afc1w, pfc1w, spa, spp);

    dim3 ga(Hd/128, Sd*Bsz/128, 2);
    k_att_mfma<<<ga, 256, 0, stream>>>(enc, encp, fc1wab, fc1wpb, spa, spp,
                                       afc1b, pfc1b, afc2w, pfc2w, ea, ep);

    k_softmax<<<dim3(Bsz,2), 256, 0, stream>>>(ea, ep);
    k_context<<<dim3(Bsz,32,2), 256, 0, stream>>>(ea, ep, enc, encp, ctx, ctxp);

    k_fcsplit<<<1536, 256, 0, stream>>>(h1, ctx, ctxp, nfcw, o1a);
    k_o1comb <<<128, 256, 0, stream>>>(o1a, nfcb, o1b);
    k_logits <<<Vd/128, 512, 0, stream>>>(o1b, fcw, fcb, logits);
  }
}